// Round 15
// baseline (278.905 us; speedup 1.0000x reference)
//
#include <hip/hip_runtime.h>
#include <hip/hip_bf16.h>

#define SS 2048
#define TT 2048
#define DD 1024
#define NB 8

typedef __attribute__((ext_vector_type(8))) short short8v;     // MFMA bf16 operand
typedef __attribute__((ext_vector_type(8))) unsigned short us8;
typedef __attribute__((ext_vector_type(4))) unsigned short us4;
typedef __attribute__((ext_vector_type(4))) float f32x4;

__device__ __forceinline__ float bf2f(unsigned short u) {
    union { unsigned int i; float f; } v; v.i = ((unsigned int)u) << 16; return v.f;
}
__device__ __forceinline__ unsigned short f2bf(float f) {
    union { float f; unsigned int i; } v; v.f = f;
    unsigned int x = v.i;
    return (unsigned short)((x + 0x7fffu + ((x >> 16) & 1u)) >> 16);
}

// ============ xbf = bf16(x), elementwise ============
__global__ __launch_bounds__(256) void conv_k(
    const float* __restrict__ in, unsigned short* __restrict__ outv, size_t n)
{
    size_t i = ((size_t)blockIdx.x * 256 + threadIdx.x) * 8;
    const size_t stride = (size_t)gridDim.x * 256 * 8;
    for (; i < n; i += stride) {
        float4 a = *reinterpret_cast<const float4*>(in + i);
        float4 b = *reinterpret_cast<const float4*>(in + i + 4);
        us8 o;
        o[0] = f2bf(a.x); o[1] = f2bf(a.y); o[2] = f2bf(a.z); o[3] = f2bf(a.w);
        o[4] = f2bf(b.x); o[5] = f2bf(b.y); o[6] = f2bf(b.z); o[7] = f2bf(b.w);
        *reinterpret_cast<us8*>(outv + i) = o;
    }
}

// ============ stateT[d][s] bf16 + statebf[s][d] bf16 from state f32 ============
__global__ __launch_bounds__(256) void transpose_k(
    const float* __restrict__ in, unsigned short* __restrict__ outT,
    unsigned short* __restrict__ outB, size_t sIn, size_t sOutT, size_t sOutB)
{
    __shared__ float t[64][65];
    const int g = blockIdx.z;
    const float* I = in + g * sIn;            // [SS][DD]
    unsigned short* OT = outT + g * sOutT;    // [DD][SS]
    unsigned short* OB = outB + g * sOutB;    // [SS][DD]
    const int s0 = blockIdx.x * 64, d0 = blockIdx.y * 64;
    const int tid = threadIdx.x;
    #pragma unroll
    for (int i = 0; i < 4; ++i) {
        int slot = tid + i * 256;
        int rr = slot >> 4, rc = (slot & 15) * 4;
        float4 v = *reinterpret_cast<const float4*>(I + (size_t)(s0 + rr) * DD + d0 + rc);
        t[rr][rc + 0] = v.x; t[rr][rc + 1] = v.y; t[rr][rc + 2] = v.z; t[rr][rc + 3] = v.w;
        us4 o; o[0] = f2bf(v.x); o[1] = f2bf(v.y); o[2] = f2bf(v.z); o[3] = f2bf(v.w);
        *reinterpret_cast<us4*>(OB + (size_t)(s0 + rr) * DD + d0 + rc) = o;
    }
    __syncthreads();
    #pragma unroll
    for (int i = 0; i < 4; ++i) {
        int slot = tid + i * 256;
        int dr = slot >> 4, sidx = (slot & 15) * 4;
        us4 o;
        #pragma unroll
        for (int j = 0; j < 4; ++j) o[j] = f2bf(t[sidx + j][dr]);
        *reinterpret_cast<us4*>(OT + (size_t)(d0 + dr) * SS + s0 + sidx) = o;
    }
}

// ============ 256x256 NT bf16 GEMM: 8 waves, BK=64, dbuf, 16x16x32 (R10) ========
template<int OUT_F32>
__global__ __launch_bounds__(512, 2) void gemm256(
    const unsigned short* __restrict__ A, const unsigned short* __restrict__ B,
    void* __restrict__ C, int lda, int ldb, int ldc, int K,
    size_t sA, size_t sB, size_t sC)
{
    __shared__ unsigned short As[2][256 * 64];
    __shared__ unsigned short Bs[2][256 * 64];

    // ---- T1 XCD swizzle (bijective; grids here are multiples of 8) ----
    const int nxy = gridDim.x * gridDim.y;
    const int nwg = nxy * gridDim.z;
    int wg = blockIdx.x + gridDim.x * (blockIdx.y + gridDim.y * blockIdx.z);
    if ((nwg & 7) == 0) {
        const int cpx = nwg >> 3;
        wg = (wg & 7) * cpx + (wg >> 3);
    }
    const int g  = wg / nxy;
    const int rm = wg - g * nxy;
    const int by = rm / gridDim.x;
    const int bx = rm - by * gridDim.x;

    const unsigned short* Ag = A + g * sA;
    const unsigned short* Bg = B + g * sB;
    const int m0 = by * 256, n0 = bx * 256;
    const int tid = threadIdx.x, lane = tid & 63, wid = tid >> 6;
    const int wr = wid >> 2, wc = wid & 3;      // wave tile: rows wr*128, cols wc*64
    const int lr = lane & 15, lkc = lane >> 4;  // frag row / k-chunk sub
    const int strow = tid >> 3;                 // staging row within 64-row slab
    const int stsp = tid & 7;                   // staging slot

    f32x4 acc[8][4] = {};
    const int NT = K >> 6;

#define STAGE256(buf, kt)                                                       \
    {                                                                           \
        const int k0 = (kt) << 6;                                               \
        _Pragma("unroll")                                                       \
        for (int j = 0; j < 4; ++j) {                                           \
            int r = j * 64 + strow;                                             \
            int c = stsp ^ (r & 7);                                             \
            __builtin_amdgcn_global_load_lds(                                   \
                (const __attribute__((address_space(1))) unsigned int*)        \
                    (Ag + (size_t)(m0 + r) * lda + k0 + c * 8),                 \
                (__attribute__((address_space(3))) unsigned int*)              \
                    (&As[buf][j * 4096 + wid * 512]),                           \
                16, 0, 0);                                                      \
        }                                                                       \
        _Pragma("unroll")                                                       \
        for (int j = 0; j < 4; ++j) {                                           \
            int r = j * 64 + strow;                                             \
            int c = stsp ^ (r & 7);                                             \
            __builtin_amdgcn_global_load_lds(                                   \
                (const __attribute__((address_space(1))) unsigned int*)        \
                    (Bg + (size_t)(n0 + r) * ldb + k0 + c * 8),                 \
                (__attribute__((address_space(3))) unsigned int*)              \
                    (&Bs[buf][j * 4096 + wid * 512]),                           \
                16, 0, 0);                                                      \
        }                                                                       \
    }

    int cur = 0;
    STAGE256(0, 0);
    __syncthreads();
    for (int kt = 0; kt < NT; ++kt) {
        if (kt + 1 < NT) STAGE256(cur ^ 1, kt + 1);
        #pragma unroll
        for (int ksub = 0; ksub < 2; ++ksub) {
            const int c0 = ksub * 4 + lkc;
            short8v a[8], bb[4];
            #pragma unroll
            for (int mi = 0; mi < 8; ++mi) {
                int r = wr * 128 + mi * 16 + lr;
                a[mi] = *reinterpret_cast<const short8v*>(
                    &As[cur][r * 64 + ((c0 ^ (r & 7)) << 3)]);
            }
            #pragma unroll
            for (int ni = 0; ni < 4; ++ni) {
                int r = wc * 64 + ni * 16 + lr;
                bb[ni] = *reinterpret_cast<const short8v*>(
                    &Bs[cur][r * 64 + ((c0 ^ (r & 7)) << 3)]);
            }
            #pragma unroll
            for (int ni = 0; ni < 4; ++ni)
                #pragma unroll
                for (int mi = 0; mi < 8; ++mi)
                    acc[mi][ni] = __builtin_amdgcn_mfma_f32_16x16x32_bf16(a[mi], bb[ni], acc[mi][ni], 0, 0, 0);
        }
        __syncthreads();
        cur ^= 1;
    }
#undef STAGE256

    const int orow = (lane >> 4) * 4, ocol = lane & 15;
    if (OUT_F32) {
        float* Cg = (float*)C + g * sC;
        #pragma unroll
        for (int mi = 0; mi < 8; ++mi)
            #pragma unroll
            for (int ni = 0; ni < 4; ++ni)
                #pragma unroll
                for (int r = 0; r < 4; ++r)
                    Cg[(size_t)(m0 + wr * 128 + mi * 16 + orow + r) * ldc + (n0 + wc * 64 + ni * 16 + ocol)] = acc[mi][ni][r];
    } else {
        unsigned short* Cg = (unsigned short*)C + g * sC;
        #pragma unroll
        for (int mi = 0; mi < 8; ++mi)
            #pragma unroll
            for (int ni = 0; ni < 4; ++ni)
                #pragma unroll
                for (int r = 0; r < 4; ++r)
                    Cg[(size_t)(m0 + wr * 128 + mi * 16 + orow + r) * ldc + (n0 + wc * 64 + ni * 16 + ocol)] = f2bf(acc[mi][ni][r]);
    }
}

// ============ 128x128 NT bf16 GEMM (K5): dbuf + prefetch + swizzle, BK=32 ======
template<int OUT_F32>
__global__ __launch_bounds__(256, 4) void gemm_nt(
    const unsigned short* __restrict__ A, const unsigned short* __restrict__ B,
    void* __restrict__ C, int lda, int ldb, int ldc, int K,
    size_t sA, size_t sB, size_t sC)
{
    __shared__ unsigned short As[2][128 * 32];
    __shared__ unsigned short Bs[2][128 * 32];

    const int nxy = gridDim.x * gridDim.y;
    const int nwg = nxy * gridDim.z;
    int wg = blockIdx.x + gridDim.x * (blockIdx.y + gridDim.y * blockIdx.z);
    if ((nwg & 7) == 0) {
        const int cpx = nwg >> 3;
        wg = (wg & 7) * cpx + (wg >> 3);
    }
    const int g  = wg / nxy;
    const int rm = wg - g * nxy;
    const int by = rm / gridDim.x;
    const int bx = rm - by * gridDim.x;

    const unsigned short* Ag = A + g * sA;
    const unsigned short* Bg = B + g * sB;
    const int m0 = by * 128, n0 = bx * 128;
    const int tid = threadIdx.x, lane = tid & 63, wid = tid >> 6;
    const int wm = (wid >> 1) * 64, wn = (wid & 1) * 64;
    const int lr16 = lane & 15, lk = lane >> 4;
    const int sr = wid * 32 + (lane >> 2);
    const int sp = lane & 3;

    f32x4 acc[4][4] = {};
    const int NT = K >> 5;

#define STAGE(buf, kt)                                                          \
    {                                                                           \
        const int k0 = (kt) << 5;                                               \
        _Pragma("unroll")                                                       \
        for (int j = 0; j < 2; ++j) {                                           \
            int r = sr + j * 16;                                                \
            int c = sp ^ ((r >> 1) & 3);                                        \
            __builtin_amdgcn_global_load_lds(                                   \
                (const __attribute__((address_space(1))) unsigned int*)        \
                    (Ag + (size_t)(m0 + r) * lda + k0 + c * 8),                 \
                (__attribute__((address_space(3))) unsigned int*)              \
                    (&As[buf][(wid * 32 + j * 16) * 32]),                       \
                16, 0, 0);                                                      \
            __builtin_amdgcn_global_load_lds(                                   \
                (const __attribute__((address_space(1))) unsigned int*)        \
                    (Bg + (size_t)(n0 + r) * ldb + k0 + c * 8),                 \
                (__attribute__((address_space(3))) unsigned int*)              \
                    (&Bs[buf][(wid * 32 + j * 16) * 32]),                       \
                16, 0, 0);                                                      \
        }                                                                       \
    }

    int cur = 0;
    STAGE(0, 0);
    __syncthreads();
    for (int kt = 0; kt < NT; ++kt) {
        if (kt + 1 < NT) STAGE(cur ^ 1, kt + 1);
        short8v a[4], bb[4];
        #pragma unroll
        for (int mi = 0; mi < 4; ++mi) {
            int r = wm + mi * 16 + lr16;
            a[mi] = *reinterpret_cast<const short8v*>(
                &As[cur][r * 32 + (lk ^ ((r >> 1) & 3)) * 8]);
        }
        #pragma unroll
        for (int ni = 0; ni < 4; ++ni) {
            int r = wn + ni * 16 + lr16;
            bb[ni] = *reinterpret_cast<const short8v*>(
                &Bs[cur][r * 32 + (lk ^ ((r >> 1) & 3)) * 8]);
        }
        #pragma unroll
        for (int ni = 0; ni < 4; ++ni)
            #pragma unroll
            for (int mi = 0; mi < 4; ++mi)
                acc[mi][ni] = __builtin_amdgcn_mfma_f32_16x16x32_bf16(a[mi], bb[ni], acc[mi][ni], 0, 0, 0);
        __syncthreads();
        cur ^= 1;
    }
#undef STAGE

    const int orow = (lane >> 4) * 4, ocol = lane & 15;
    if (OUT_F32) {
        float* Cg = (float*)C + g * sC;
        #pragma unroll
        for (int mi = 0; mi < 4; ++mi)
            #pragma unroll
            for (int ni = 0; ni < 4; ++ni)
                #pragma unroll
                for (int r = 0; r < 4; ++r)
                    Cg[(size_t)(m0 + wm + mi * 16 + orow + r) * ldc + (n0 + wn + ni * 16 + ocol)] = acc[mi][ni][r];
    } else {
        unsigned short* Cg = (unsigned short*)C + g * sC;
        #pragma unroll
        for (int mi = 0; mi < 4; ++mi)
            #pragma unroll
            for (int ni = 0; ni < 4; ++ni)
                #pragma unroll
                for (int r = 0; r < 4; ++r)
                    Cg[(size_t)(m0 + wm + mi * 16 + orow + r) * ldc + (n0 + wn + ni * 16 + ocol)] = f2bf(acc[mi][ni][r]);
    }
}

// ============ FUSED: softmax over s + sparse w = p^T state ============
// Per t-row: find window (scores within 16 of max), fp32-recompute those
// dots, softmax over WINDOW ONLY (tail mass < 2.3e-4, below bf16 quantum of w),
// then w[t,:] = sum_j p_j * statebf[s_j,:]  (fp32 accum, bf16 store).
// Masked t rows skipped entirely (discarded by second mask downstream).
__global__ __launch_bounds__(256) void softmax1w(
    const unsigned short* __restrict__ P, const float* __restrict__ x,
    const float* __restrict__ state, const unsigned short* __restrict__ statebf,
    unsigned short* __restrict__ w, const int* __restrict__ src,
    int b0, size_t sP, size_t sSB, size_t sW)
{
    const int t = blockIdx.x, g = blockIdx.y, b = b0 + g, tid = threadIdx.x;
    const int lane = tid & 63, wid = tid >> 6;
    const int* sb = src + (size_t)b * SS;
    if (sb[t] == 0) return;   // whole block exits together (t uniform)

    const unsigned short* row = P + g * sP + (size_t)t * SS;
    __shared__ float redA[4];
    __shared__ int cnt, list[96];
    __shared__ float corr[96];

    us8 rv = *reinterpret_cast<const us8*>(row + tid * 8);
    int4 mk0 = reinterpret_cast<const int4*>(sb)[tid * 2];
    int4 mk1 = reinterpret_cast<const int4*>(sb)[tid * 2 + 1];
    int msk[8] = { mk0.x == 0, mk0.y == 0, mk0.z == 0, mk0.w == 0,
                   mk1.x == 0, mk1.y == 0, mk1.z == 0, mk1.w == 0 };
    float v[8];
    float m = -1e30f;
    #pragma unroll
    for (int i = 0; i < 8; ++i) {
        v[i] = msk[i] ? -1e30f : bf2f(rv[i]);
        m = fmaxf(m, v[i]);
    }
    #pragma unroll
    for (int o = 32; o > 0; o >>= 1) m = fmaxf(m, __shfl_xor(m, o, 64));
    if (lane == 0) redA[wid] = m;
    if (tid == 0) cnt = 0;
    __syncthreads();
    const float M = fmaxf(fmaxf(redA[0], redA[1]), fmaxf(redA[2], redA[3]));
    // flag entries within 16 of max (bf16 dot error << 16)
    #pragma unroll
    for (int i = 0; i < 8; ++i) {
        if (!msk[i] && v[i] > M - 16.f) {
            int j = atomicAdd(&cnt, 1);
            if (j < 96) list[j] = tid * 8 + i;
        }
    }
    __syncthreads();
    const int n = min(cnt, 96);
    // fp32 re-dot of flagged entries: wave j handles list[j]
    const float* xr = x + (size_t)b * SS * DD + (size_t)t * DD;
    float4 xa[4];
    #pragma unroll
    for (int c = 0; c < 4; ++c) xa[c] = reinterpret_cast<const float4*>(xr)[lane + c * 64];
    for (int j = wid; j < n; j += 4) {
        const float* sr = state + (size_t)b * SS * DD + (size_t)list[j] * DD;
        float p = 0.f;
        #pragma unroll
        for (int c = 0; c < 4; ++c) {
            float4 c4 = reinterpret_cast<const float4*>(sr)[lane + c * 64];
            p += xa[c].x * c4.x + xa[c].y * c4.y + xa[c].z * c4.z + xa[c].w * c4.w;
        }
        #pragma unroll
        for (int o = 32; o > 0; o >>= 1) p += __shfl_xor(p, o, 64);
        if (lane == 0) corr[j] = p;
    }
    __syncthreads();
    // window softmax: M2/L over corrected scores (identical serial scan per thread)
    unsigned short* wrow = w + g * sW + (size_t)t * DD;
    if (n == 0) {   // only possible if all s masked (prob ~0) — write zeros
        us4 z = {0, 0, 0, 0};
        *reinterpret_cast<us4*>(wrow + tid * 4) = z;
        return;
    }
    float M2 = -1e30f;
    for (int j = 0; j < n; ++j) M2 = fmaxf(M2, corr[j]);
    float L = 0.f;
    for (int j = 0; j < n; ++j) L += __expf(corr[j] - M2);
    const float invL = 1.f / L;
    if (tid < n) corr[tid] = __expf(corr[tid] - M2) * invL;   // corr := p_j
    __syncthreads();
    // w[t, tid*4 .. +4) = sum_j p_j * statebf[s_j, :]
    const unsigned short* SBg = statebf + g * sSB;
    float a0 = 0.f, a1 = 0.f, a2 = 0.f, a3 = 0.f;
    for (int j = 0; j < n; ++j) {
        float pj = corr[j];
        us4 sv = *reinterpret_cast<const us4*>(SBg + (size_t)list[j] * DD + tid * 4);
        a0 += pj * bf2f(sv[0]);
        a1 += pj * bf2f(sv[1]);
        a2 += pj * bf2f(sv[2]);
        a3 += pj * bf2f(sv[3]);
    }
    us4 ov; ov[0] = f2bf(a0); ov[1] = f2bf(a1); ov[2] = f2bf(a2); ov[3] = f2bf(a3);
    *reinterpret_cast<us4*>(wrow + tid * 4) = ov;
}

// ============ bf16 transpose: w [TT][DD] -> wT [DD][TT], per g ============
__global__ __launch_bounds__(256) void transpose_bf(
    const unsigned short* __restrict__ in, unsigned short* __restrict__ out,
    size_t sIn, size_t sOut)
{
    __shared__ unsigned short tle[64][66];
    const int g = blockIdx.z;
    const unsigned short* I = in + g * sIn;
    unsigned short* O = out + g * sOut;
    const int t0 = blockIdx.x * 64, d0 = blockIdx.y * 64;
    const int tid = threadIdx.x;
    #pragma unroll
    for (int i = 0; i < 4; ++i) {
        int slot = tid + i * 256;
        int rr = slot >> 4, rc = (slot & 15) * 4;
        us4 v = *reinterpret_cast<const us4*>(I + (size_t)(t0 + rr) * DD + d0 + rc);
        tle[rr][rc + 0] = v[0]; tle[rr][rc + 1] = v[1];
        tle[rr][rc + 2] = v[2]; tle[rr][rc + 3] = v[3];
    }
    __syncthreads();
    #pragma unroll
    for (int i = 0; i < 4; ++i) {
        int slot = tid + i * 256;
        int dr = slot >> 4, tc = (slot & 15) * 4;
        us4 o;
        #pragma unroll
        for (int j = 0; j < 4; ++j) o[j] = tle[tc + j][dr];
        *reinterpret_cast<us4*>(O + (size_t)(d0 + dr) * TT + t0 + tc) = o;
    }
}

// ============ K4: row softmax over t (masked), wT bf16 -> attnT bf16 ============
__global__ __launch_bounds__(256) void softmax2_k(
    const unsigned short* __restrict__ wT, unsigned short* __restrict__ attnT,
    const int* __restrict__ src, int b0, size_t sW, size_t sAt)
{
    const int e = blockIdx.x, g = blockIdx.y, b = b0 + g, tid = threadIdx.x;
    const int lane = tid & 63, wid = tid >> 6;
    const unsigned short* row = wT + g * sW + (size_t)e * TT;
    unsigned short* orow = attnT + g * sAt + (size_t)e * TT;
    const int* sb = src + (size_t)b * SS;
    __shared__ float shm[4], shl[4];
    us8 rv = *reinterpret_cast<const us8*>(row + tid * 8);
    int4 mk0 = reinterpret_cast<const int4*>(sb)[tid * 2];
    int4 mk1 = reinterpret_cast<const int4*>(sb)[tid * 2 + 1];
    int msk[8] = { mk0.x == 0, mk0.y == 0, mk0.z == 0, mk0.w == 0,
                   mk1.x == 0, mk1.y == 0, mk1.z == 0, mk1.w == 0 };
    float v[8];
    float m = -1e30f;
    #pragma unroll
    for (int i = 0; i < 8; ++i) {
        v[i] = msk[i] ? -1e30f : bf2f(rv[i]);
        m = fmaxf(m, v[i]);
    }
    #pragma unroll
    for (int o = 32; o > 0; o >>= 1) m = fmaxf(m, __shfl_xor(m, o, 64));
    if (lane == 0) shm[wid] = m;
    __syncthreads();
    const float M = fmaxf(fmaxf(shm[0], shm[1]), fmaxf(shm[2], shm[3]));
    float l = 0.f;
    #pragma unroll
    for (int i = 0; i < 8; ++i) if (!msk[i]) { v[i] = __expf(v[i] - M); l += v[i]; }
    #pragma unroll
    for (int o = 32; o > 0; o >>= 1) l += __shfl_xor(l, o, 64);
    if (lane == 0) shl[wid] = l;
    __syncthreads();
    const float inv = 1.f / (shl[0] + shl[1] + shl[2] + shl[3]);
    us8 ov;
    #pragma unroll
    for (int i = 0; i < 8; ++i) ov[i] = msk[i] ? 0 : f2bf(v[i] * inv);
    *reinterpret_cast<us8*>(orow + tid * 8) = ov;
}

extern "C" void kernel_launch(void* const* d_in, const int* in_sizes, int n_in,
                              void* d_out, int out_size, void* d_ws, size_t ws_size,
                              hipStream_t stream)
{
    const float* state = (const float*)d_in[0];
    const float* x     = (const float*)d_in[1];
    const int* src     = (const int*)d_in[2];
    float* out         = (float*)d_out;

    const size_t SD = (size_t)SS * DD;
    const size_t perP  = (size_t)SS * TT * 2;   // scores, later wT (needs DD*TT*2 <= perP)
    const size_t perST = (size_t)DD * SS * 2;
    const size_t perW  = (size_t)DD * TT * 2;   // w [t][d], later attnT [e][t]
    const size_t perXB = (size_t)SS * DD * 2;
    const size_t perSB = (size_t)SS * DD * 2;
    const size_t perBatch = perP + perST + perW + perXB + perSB;

    int G = 8;
    while (G > 1 && (size_t)G * perBatch > ws_size) G >>= 1;

    char* base = (char*)d_ws;
    unsigned short* P  = (unsigned short*)base;
    unsigned short* ST = (unsigned short*)(base + (size_t)G * perP);
    unsigned short* W  = (unsigned short*)(base + (size_t)G * (perP + perST));
    unsigned short* XB = (unsigned short*)(base + (size_t)G * (perP + perST + perW));
    unsigned short* SB = (unsigned short*)(base + (size_t)G * (perP + perST + perW + perXB));

    const size_t sP  = (size_t)SS * TT;
    const size_t sST = (size_t)DD * SS;
    const size_t sW  = (size_t)DD * TT;
    const size_t sXB = (size_t)SS * DD;

    for (int b0 = 0; b0 < NB; b0 += G) {
        conv_k<<<2048, 256, 0, stream>>>(x + (size_t)b0 * SD, XB, (size_t)G * SD);
        transpose_k<<<dim3(SS / 64, DD / 64, G), 256, 0, stream>>>(
            state + (size_t)b0 * SD, ST, SB, SD, sST, sXB);

        // K1: scoresT[t][s] = xbf . statebf^T   (bf16 out into P), 256^2 tile
        gemm256<0><<<dim3(SS / 256, TT / 256, G), 512, 0, stream>>>(
            XB, SB, P, DD, DD, SS, DD, sXB, sXB, sP);

        // K2+K3 fused: window softmax + sparse w[t][d] = p^T statebf (into W)
        softmax1w<<<dim3(TT, G), 256, 0, stream>>>(
            P, x, state, SB, W, src, b0, sP, sXB, sW);

        // transpose: w [t][d] -> wT [d][t] (into P region; scores dead)
        transpose_bf<<<dim3(TT / 64, DD / 64, G), 256, 0, stream>>>(W, P, sW, sP);

        // K4: softmax over t per row e; attnT into W (w dead)
        softmax2_k<<<dim3(DD, G), 256, 0, stream>>>(P, W, src, b0, sP, sW);

        // K5: out[e][d] = attnT . stateT^T   (fp32 out, direct), 128^2 tile
        gemm_nt<1><<<dim3(DD / 128, DD / 128, G), 256, 0, stream>>>(
            W, ST, out + (size_t)b0 * DD * DD, TT, SS, DD, TT, sW, sST, (size_t)DD * DD);
    }
}

// Round 16
// 275.300 us; speedup vs baseline: 1.0131x; 1.0131x over previous
//
#include <hip/hip_runtime.h>
#include <hip/hip_bf16.h>

#define SS 2048
#define TT 2048
#define DD 1024
#define NB 8

typedef __attribute__((ext_vector_type(8))) short short8v;     // MFMA bf16 operand
typedef __attribute__((ext_vector_type(8))) unsigned short us8;
typedef __attribute__((ext_vector_type(4))) unsigned short us4;
typedef __attribute__((ext_vector_type(4))) float f32x4;

__device__ __forceinline__ float bf2f(unsigned short u) {
    union { unsigned int i; float f; } v; v.i = ((unsigned int)u) << 16; return v.f;
}
__device__ __forceinline__ unsigned short f2bf(float f) {
    union { float f; unsigned int i; } v; v.f = f;
    unsigned int x = v.i;
    return (unsigned short)((x + 0x7fffu + ((x >> 16) & 1u)) >> 16);
}

// ============ xbf = bf16(x), elementwise ============
__global__ __launch_bounds__(256) void conv_k(
    const float* __restrict__ in, unsigned short* __restrict__ outv, size_t n)
{
    size_t i = ((size_t)blockIdx.x * 256 + threadIdx.x) * 8;
    const size_t stride = (size_t)gridDim.x * 256 * 8;
    for (; i < n; i += stride) {
        float4 a = *reinterpret_cast<const float4*>(in + i);
        float4 b = *reinterpret_cast<const float4*>(in + i + 4);
        us8 o;
        o[0] = f2bf(a.x); o[1] = f2bf(a.y); o[2] = f2bf(a.z); o[3] = f2bf(a.w);
        o[4] = f2bf(b.x); o[5] = f2bf(b.y); o[6] = f2bf(b.z); o[7] = f2bf(b.w);
        *reinterpret_cast<us8*>(outv + i) = o;
    }
}

// ============ stateT[d][s] bf16 + statebf[s][d] bf16 from state f32 ============
__global__ __launch_bounds__(256) void transpose_k(
    const float* __restrict__ in, unsigned short* __restrict__ outT,
    unsigned short* __restrict__ outB, size_t sIn, size_t sOutT, size_t sOutB)
{
    __shared__ float t[64][65];
    const int g = blockIdx.z;
    const float* I = in + g * sIn;            // [SS][DD]
    unsigned short* OT = outT + g * sOutT;    // [DD][SS]
    unsigned short* OB = outB + g * sOutB;    // [SS][DD]
    const int s0 = blockIdx.x * 64, d0 = blockIdx.y * 64;
    const int tid = threadIdx.x;
    #pragma unroll
    for (int i = 0; i < 4; ++i) {
        int slot = tid + i * 256;
        int rr = slot >> 4, rc = (slot & 15) * 4;
        float4 v = *reinterpret_cast<const float4*>(I + (size_t)(s0 + rr) * DD + d0 + rc);
        t[rr][rc + 0] = v.x; t[rr][rc + 1] = v.y; t[rr][rc + 2] = v.z; t[rr][rc + 3] = v.w;
        us4 o; o[0] = f2bf(v.x); o[1] = f2bf(v.y); o[2] = f2bf(v.z); o[3] = f2bf(v.w);
        *reinterpret_cast<us4*>(OB + (size_t)(s0 + rr) * DD + d0 + rc) = o;
    }
    __syncthreads();
    #pragma unroll
    for (int i = 0; i < 4; ++i) {
        int slot = tid + i * 256;
        int dr = slot >> 4, sidx = (slot & 15) * 4;
        us4 o;
        #pragma unroll
        for (int j = 0; j < 4; ++j) o[j] = f2bf(t[sidx + j][dr]);
        *reinterpret_cast<us4*>(OT + (size_t)(d0 + dr) * SS + s0 + sidx) = o;
    }
}

// ============ 256x256 NT bf16 GEMM: 8 waves, BK=64, dbuf, 16x16x32 (R10) ========
template<int OUT_F32>
__global__ __launch_bounds__(512, 2) void gemm256(
    const unsigned short* __restrict__ A, const unsigned short* __restrict__ B,
    void* __restrict__ C, int lda, int ldb, int ldc, int K,
    size_t sA, size_t sB, size_t sC)
{
    __shared__ unsigned short As[2][256 * 64];
    __shared__ unsigned short Bs[2][256 * 64];

    // ---- T1 XCD swizzle (bijective; grids here are multiples of 8) ----
    const int nxy = gridDim.x * gridDim.y;
    const int nwg = nxy * gridDim.z;
    int wg = blockIdx.x + gridDim.x * (blockIdx.y + gridDim.y * blockIdx.z);
    if ((nwg & 7) == 0) {
        const int cpx = nwg >> 3;
        wg = (wg & 7) * cpx + (wg >> 3);
    }
    const int g  = wg / nxy;
    const int rm = wg - g * nxy;
    const int by = rm / gridDim.x;
    const int bx = rm - by * gridDim.x;

    const unsigned short* Ag = A + g * sA;
    const unsigned short* Bg = B + g * sB;
    const int m0 = by * 256, n0 = bx * 256;
    const int tid = threadIdx.x, lane = tid & 63, wid = tid >> 6;
    const int wr = wid >> 2, wc = wid & 3;      // wave tile: rows wr*128, cols wc*64
    const int lr = lane & 15, lkc = lane >> 4;  // frag row / k-chunk sub
    const int strow = tid >> 3;                 // staging row within 64-row slab
    const int stsp = tid & 7;                   // staging slot

    f32x4 acc[8][4] = {};
    const int NT = K >> 6;

#define STAGE256(buf, kt)                                                       \
    {                                                                           \
        const int k0 = (kt) << 6;                                               \
        _Pragma("unroll")                                                       \
        for (int j = 0; j < 4; ++j) {                                           \
            int r = j * 64 + strow;                                             \
            int c = stsp ^ (r & 7);                                             \
            __builtin_amdgcn_global_load_lds(                                   \
                (const __attribute__((address_space(1))) unsigned int*)        \
                    (Ag + (size_t)(m0 + r) * lda + k0 + c * 8),                 \
                (__attribute__((address_space(3))) unsigned int*)              \
                    (&As[buf][j * 4096 + wid * 512]),                           \
                16, 0, 0);                                                      \
        }                                                                       \
        _Pragma("unroll")                                                       \
        for (int j = 0; j < 4; ++j) {                                           \
            int r = j * 64 + strow;                                             \
            int c = stsp ^ (r & 7);                                             \
            __builtin_amdgcn_global_load_lds(                                   \
                (const __attribute__((address_space(1))) unsigned int*)        \
                    (Bg + (size_t)(n0 + r) * ldb + k0 + c * 8),                 \
                (__attribute__((address_space(3))) unsigned int*)              \
                    (&Bs[buf][j * 4096 + wid * 512]),                           \
                16, 0, 0);                                                      \
        }                                                                       \
    }

    int cur = 0;
    STAGE256(0, 0);
    __syncthreads();
    for (int kt = 0; kt < NT; ++kt) {
        if (kt + 1 < NT) STAGE256(cur ^ 1, kt + 1);
        #pragma unroll
        for (int ksub = 0; ksub < 2; ++ksub) {
            const int c0 = ksub * 4 + lkc;
            short8v a[8], bb[4];
            #pragma unroll
            for (int mi = 0; mi < 8; ++mi) {
                int r = wr * 128 + mi * 16 + lr;
                a[mi] = *reinterpret_cast<const short8v*>(
                    &As[cur][r * 64 + ((c0 ^ (r & 7)) << 3)]);
            }
            #pragma unroll
            for (int ni = 0; ni < 4; ++ni) {
                int r = wc * 64 + ni * 16 + lr;
                bb[ni] = *reinterpret_cast<const short8v*>(
                    &Bs[cur][r * 64 + ((c0 ^ (r & 7)) << 3)]);
            }
            #pragma unroll
            for (int ni = 0; ni < 4; ++ni)
                #pragma unroll
                for (int mi = 0; mi < 8; ++mi)
                    acc[mi][ni] = __builtin_amdgcn_mfma_f32_16x16x32_bf16(a[mi], bb[ni], acc[mi][ni], 0, 0, 0);
        }
        __syncthreads();
        cur ^= 1;
    }
#undef STAGE256

    const int orow = (lane >> 4) * 4, ocol = lane & 15;
    if (OUT_F32) {
        float* Cg = (float*)C + g * sC;
        #pragma unroll
        for (int mi = 0; mi < 8; ++mi)
            #pragma unroll
            for (int ni = 0; ni < 4; ++ni)
                #pragma unroll
                for (int r = 0; r < 4; ++r)
                    Cg[(size_t)(m0 + wr * 128 + mi * 16 + orow + r) * ldc + (n0 + wc * 64 + ni * 16 + ocol)] = acc[mi][ni][r];
    } else {
        unsigned short* Cg = (unsigned short*)C + g * sC;
        #pragma unroll
        for (int mi = 0; mi < 8; ++mi)
            #pragma unroll
            for (int ni = 0; ni < 4; ++ni)
                #pragma unroll
                for (int r = 0; r < 4; ++r)
                    Cg[(size_t)(m0 + wr * 128 + mi * 16 + orow + r) * ldc + (n0 + wc * 64 + ni * 16 + ocol)] = f2bf(acc[mi][ni][r]);
    }
}

// ============ 128x128 NT bf16 GEMM (K5): dbuf + prefetch + swizzle, BK=32 ======
template<int OUT_F32>
__global__ __launch_bounds__(256, 4) void gemm_nt(
    const unsigned short* __restrict__ A, const unsigned short* __restrict__ B,
    void* __restrict__ C, int lda, int ldb, int ldc, int K,
    size_t sA, size_t sB, size_t sC)
{
    __shared__ unsigned short As[2][128 * 32];
    __shared__ unsigned short Bs[2][128 * 32];

    const int nxy = gridDim.x * gridDim.y;
    const int nwg = nxy * gridDim.z;
    int wg = blockIdx.x + gridDim.x * (blockIdx.y + gridDim.y * blockIdx.z);
    if ((nwg & 7) == 0) {
        const int cpx = nwg >> 3;
        wg = (wg & 7) * cpx + (wg >> 3);
    }
    const int g  = wg / nxy;
    const int rm = wg - g * nxy;
    const int by = rm / gridDim.x;
    const int bx = rm - by * gridDim.x;

    const unsigned short* Ag = A + g * sA;
    const unsigned short* Bg = B + g * sB;
    const int m0 = by * 128, n0 = bx * 128;
    const int tid = threadIdx.x, lane = tid & 63, wid = tid >> 6;
    const int wm = (wid >> 1) * 64, wn = (wid & 1) * 64;
    const int lr16 = lane & 15, lk = lane >> 4;
    const int sr = wid * 32 + (lane >> 2);
    const int sp = lane & 3;

    f32x4 acc[4][4] = {};
    const int NT = K >> 5;

#define STAGE(buf, kt)                                                          \
    {                                                                           \
        const int k0 = (kt) << 5;                                               \
        _Pragma("unroll")                                                       \
        for (int j = 0; j < 2; ++j) {                                           \
            int r = sr + j * 16;                                                \
            int c = sp ^ ((r >> 1) & 3);                                        \
            __builtin_amdgcn_global_load_lds(                                   \
                (const __attribute__((address_space(1))) unsigned int*)        \
                    (Ag + (size_t)(m0 + r) * lda + k0 + c * 8),                 \
                (__attribute__((address_space(3))) unsigned int*)              \
                    (&As[buf][(wid * 32 + j * 16) * 32]),                       \
                16, 0, 0);                                                      \
            __builtin_amdgcn_global_load_lds(                                   \
                (const __attribute__((address_space(1))) unsigned int*)        \
                    (Bg + (size_t)(n0 + r) * ldb + k0 + c * 8),                 \
                (__attribute__((address_space(3))) unsigned int*)              \
                    (&Bs[buf][(wid * 32 + j * 16) * 32]),                       \
                16, 0, 0);                                                      \
        }                                                                       \
    }

    int cur = 0;
    STAGE(0, 0);
    __syncthreads();
    for (int kt = 0; kt < NT; ++kt) {
        if (kt + 1 < NT) STAGE(cur ^ 1, kt + 1);
        short8v a[4], bb[4];
        #pragma unroll
        for (int mi = 0; mi < 4; ++mi) {
            int r = wm + mi * 16 + lr16;
            a[mi] = *reinterpret_cast<const short8v*>(
                &As[cur][r * 32 + (lk ^ ((r >> 1) & 3)) * 8]);
        }
        #pragma unroll
        for (int ni = 0; ni < 4; ++ni) {
            int r = wn + ni * 16 + lr16;
            bb[ni] = *reinterpret_cast<const short8v*>(
                &Bs[cur][r * 32 + (lk ^ ((r >> 1) & 3)) * 8]);
        }
        #pragma unroll
        for (int ni = 0; ni < 4; ++ni)
            #pragma unroll
            for (int mi = 0; mi < 4; ++mi)
                acc[mi][ni] = __builtin_amdgcn_mfma_f32_16x16x32_bf16(a[mi], bb[ni], acc[mi][ni], 0, 0, 0);
        __syncthreads();
        cur ^= 1;
    }
#undef STAGE

    const int orow = (lane >> 4) * 4, ocol = lane & 15;
    if (OUT_F32) {
        float* Cg = (float*)C + g * sC;
        #pragma unroll
        for (int mi = 0; mi < 4; ++mi)
            #pragma unroll
            for (int ni = 0; ni < 4; ++ni)
                #pragma unroll
                for (int r = 0; r < 4; ++r)
                    Cg[(size_t)(m0 + wm + mi * 16 + orow + r) * ldc + (n0 + wn + ni * 16 + ocol)] = acc[mi][ni][r];
    } else {
        unsigned short* Cg = (unsigned short*)C + g * sC;
        #pragma unroll
        for (int mi = 0; mi < 4; ++mi)
            #pragma unroll
            for (int ni = 0; ni < 4; ++ni)
                #pragma unroll
                for (int r = 0; r < 4; ++r)
                    Cg[(size_t)(m0 + wm + mi * 16 + orow + r) * ldc + (n0 + wn + ni * 16 + ocol)] = f2bf(acc[mi][ni][r]);
    }
}

// ============ FUSED: softmax over s + sparse w = p^T state ============
// Per t-row: find window (scores within 16 of max), fp32-recompute those
// dots, softmax over WINDOW ONLY (tail mass < 2.3e-4, below bf16 quantum of w),
// then w[t,:] = sum_j p_j * statebf[s_j,:]  (fp32 accum, bf16 store).
// Masked t rows skipped entirely (discarded by second mask downstream).
__global__ __launch_bounds__(256) void softmax1w(
    const unsigned short* __restrict__ P, const float* __restrict__ x,
    const float* __restrict__ state, const unsigned short* __restrict__ statebf,
    unsigned short* __restrict__ w, const int* __restrict__ src,
    int b0, size_t sP, size_t sSB, size_t sW)
{
    const int t = blockIdx.x, g = blockIdx.y, b = b0 + g, tid = threadIdx.x;
    const int lane = tid & 63, wid = tid >> 6;
    const int* sb = src + (size_t)b * SS;
    if (sb[t] == 0) return;   // whole block exits together (t uniform)

    const unsigned short* row = P + g * sP + (size_t)t * SS;
    __shared__ float redA[4];
    __shared__ int cnt, list[96];
    __shared__ float corr[96];

    us8 rv = *reinterpret_cast<const us8*>(row + tid * 8);
    int4 mk0 = reinterpret_cast<const int4*>(sb)[tid * 2];
    int4 mk1 = reinterpret_cast<const int4*>(sb)[tid * 2 + 1];
    int msk[8] = { mk0.x == 0, mk0.y == 0, mk0.z == 0, mk0.w == 0,
                   mk1.x == 0, mk1.y == 0, mk1.z == 0, mk1.w == 0 };
    float v[8];
    float m = -1e30f;
    #pragma unroll
    for (int i = 0; i < 8; ++i) {
        v[i] = msk[i] ? -1e30f : bf2f(rv[i]);
        m = fmaxf(m, v[i]);
    }
    #pragma unroll
    for (int o = 32; o > 0; o >>= 1) m = fmaxf(m, __shfl_xor(m, o, 64));
    if (lane == 0) redA[wid] = m;
    if (tid == 0) cnt = 0;
    __syncthreads();
    const float M = fmaxf(fmaxf(redA[0], redA[1]), fmaxf(redA[2], redA[3]));
    // flag entries within 16 of max (bf16 dot error << 16)
    #pragma unroll
    for (int i = 0; i < 8; ++i) {
        if (!msk[i] && v[i] > M - 16.f) {
            int j = atomicAdd(&cnt, 1);
            if (j < 96) list[j] = tid * 8 + i;
        }
    }
    __syncthreads();
    const int n = min(cnt, 96);
    // fp32 re-dot of flagged entries: wave j handles list[j]
    const float* xr = x + (size_t)b * SS * DD + (size_t)t * DD;
    float4 xa[4];
    #pragma unroll
    for (int c = 0; c < 4; ++c) xa[c] = reinterpret_cast<const float4*>(xr)[lane + c * 64];
    for (int j = wid; j < n; j += 4) {
        const float* sr = state + (size_t)b * SS * DD + (size_t)list[j] * DD;
        float p = 0.f;
        #pragma unroll
        for (int c = 0; c < 4; ++c) {
            float4 c4 = reinterpret_cast<const float4*>(sr)[lane + c * 64];
            p += xa[c].x * c4.x + xa[c].y * c4.y + xa[c].z * c4.z + xa[c].w * c4.w;
        }
        #pragma unroll
        for (int o = 32; o > 0; o >>= 1) p += __shfl_xor(p, o, 64);
        if (lane == 0) corr[j] = p;
    }
    __syncthreads();
    // window softmax: M2/L over corrected scores (identical serial scan per thread)
    unsigned short* wrow = w + g * sW + (size_t)t * DD;
    if (n == 0) {   // only possible if all s masked (prob ~0) — write zeros
        us4 z = {0, 0, 0, 0};
        *reinterpret_cast<us4*>(wrow + tid * 4) = z;
        return;
    }
    float M2 = -1e30f;
    for (int j = 0; j < n; ++j) M2 = fmaxf(M2, corr[j]);
    float L = 0.f;
    for (int j = 0; j < n; ++j) L += __expf(corr[j] - M2);
    const float invL = 1.f / L;
    if (tid < n) corr[tid] = __expf(corr[tid] - M2) * invL;   // corr := p_j
    __syncthreads();
    // w[t, tid*4 .. +4) = sum_j p_j * statebf[s_j, :]
    const unsigned short* SBg = statebf + g * sSB;
    float a0 = 0.f, a1 = 0.f, a2 = 0.f, a3 = 0.f;
    for (int j = 0; j < n; ++j) {
        float pj = corr[j];
        us4 sv = *reinterpret_cast<const us4*>(SBg + (size_t)list[j] * DD + tid * 4);
        a0 += pj * bf2f(sv[0]);
        a1 += pj * bf2f(sv[1]);
        a2 += pj * bf2f(sv[2]);
        a3 += pj * bf2f(sv[3]);
    }
    us4 ov; ov[0] = f2bf(a0); ov[1] = f2bf(a1); ov[2] = f2bf(a2); ov[3] = f2bf(a3);
    *reinterpret_cast<us4*>(wrow + tid * 4) = ov;
}

// ============ bf16 transpose: w [TT][DD] -> wT [DD][TT], per g ============
__global__ __launch_bounds__(256) void transpose_bf(
    const unsigned short* __restrict__ in, unsigned short* __restrict__ out,
    size_t sIn, size_t sOut)
{
    __shared__ unsigned short tle[64][66];
    const int g = blockIdx.z;
    const unsigned short* I = in + g * sIn;
    unsigned short* O = out + g * sOut;
    const int t0 = blockIdx.x * 64, d0 = blockIdx.y * 64;
    const int tid = threadIdx.x;
    #pragma unroll
    for (int i = 0; i < 4; ++i) {
        int slot = tid + i * 256;
        int rr = slot >> 4, rc = (slot & 15) * 4;
        us4 v = *reinterpret_cast<const us4*>(I + (size_t)(t0 + rr) * DD + d0 + rc);
        tle[rr][rc + 0] = v[0]; tle[rr][rc + 1] = v[1];
        tle[rr][rc + 2] = v[2]; tle[rr][rc + 3] = v[3];
    }
    __syncthreads();
    #pragma unroll
    for (int i = 0; i < 4; ++i) {
        int slot = tid + i * 256;
        int dr = slot >> 4, tc = (slot & 15) * 4;
        us4 o;
        #pragma unroll
        for (int j = 0; j < 4; ++j) o[j] = tle[tc + j][dr];
        *reinterpret_cast<us4*>(O + (size_t)(d0 + dr) * TT + t0 + tc) = o;
    }
}

// ============ K4: row softmax over t (masked), wT bf16 -> attnT bf16 ============
__global__ __launch_bounds__(256) void softmax2_k(
    const unsigned short* __restrict__ wT, unsigned short* __restrict__ attnT,
    const int* __restrict__ src, int b0, size_t sW, size_t sAt)
{
    const int e = blockIdx.x, g = blockIdx.y, b = b0 + g, tid = threadIdx.x;
    const int lane = tid & 63, wid = tid >> 6;
    const unsigned short* row = wT + g * sW + (size_t)e * TT;
    unsigned short* orow = attnT + g * sAt + (size_t)e * TT;
    const int* sb = src + (size_t)b * SS;
    __shared__ float shm[4], shl[4];
    us8 rv = *reinterpret_cast<const us8*>(row + tid * 8);
    int4 mk0 = reinterpret_cast<const int4*>(sb)[tid * 2];
    int4 mk1 = reinterpret_cast<const int4*>(sb)[tid * 2 + 1];
    int msk[8] = { mk0.x == 0, mk0.y == 0, mk0.z == 0, mk0.w == 0,
                   mk1.x == 0, mk1.y == 0, mk1.z == 0, mk1.w == 0 };
    float v[8];
    float m = -1e30f;
    #pragma unroll
    for (int i = 0; i < 8; ++i) {
        v[i] = msk[i] ? -1e30f : bf2f(rv[i]);
        m = fmaxf(m, v[i]);
    }
    #pragma unroll
    for (int o = 32; o > 0; o >>= 1) m = fmaxf(m, __shfl_xor(m, o, 64));
    if (lane == 0) shm[wid] = m;
    __syncthreads();
    const float M = fmaxf(fmaxf(shm[0], shm[1]), fmaxf(shm[2], shm[3]));
    float l = 0.f;
    #pragma unroll
    for (int i = 0; i < 8; ++i) if (!msk[i]) { v[i] = __expf(v[i] - M); l += v[i]; }
    #pragma unroll
    for (int o = 32; o > 0; o >>= 1) l += __shfl_xor(l, o, 64);
    if (lane == 0) shl[wid] = l;
    __syncthreads();
    const float inv = 1.f / (shl[0] + shl[1] + shl[2] + shl[3]);
    us8 ov;
    #pragma unroll
    for (int i = 0; i < 8; ++i) ov[i] = msk[i] ? 0 : f2bf(v[i] * inv);
    *reinterpret_cast<us8*>(orow + tid * 8) = ov;
}

extern "C" void kernel_launch(void* const* d_in, const int* in_sizes, int n_in,
                              void* d_out, int out_size, void* d_ws, size_t ws_size,
                              hipStream_t stream)
{
    const float* state = (const float*)d_in[0];
    const float* x     = (const float*)d_in[1];
    const int* src     = (const int*)d_in[2];
    float* out         = (float*)d_out;

    const size_t SD = (size_t)SS * DD;
    const size_t perP  = (size_t)SS * TT * 2;   // scores, later wT (needs DD*TT*2 <= perP)
    const size_t perST = (size_t)DD * SS * 2;
    const size_t perW  = (size_t)DD * TT * 2;   // w [t][d], later attnT [e][t]
    const size_t perXB = (size_t)SS * DD * 2;
    const size_t perSB = (size_t)SS * DD * 2;
    const size_t perBatch = perP + perST + perW + perXB + perSB;

    int G = 8;
    while (G > 1 && (size_t)G * perBatch > ws_size) G >>= 1;

    char* base = (char*)d_ws;
    unsigned short* P  = (unsigned short*)base;
    unsigned short* ST = (unsigned short*)(base + (size_t)G * perP);
    unsigned short* W  = (unsigned short*)(base + (size_t)G * (perP + perST));
    unsigned short* XB = (unsigned short*)(base + (size_t)G * (perP + perST + perW));
    unsigned short* SB = (unsigned short*)(base + (size_t)G * (perP + perST + perW + perXB));

    const size_t sP  = (size_t)SS * TT;
    const size_t sST = (size_t)DD * SS;
    const size_t sW  = (size_t)DD * TT;
    const size_t sXB = (size_t)SS * DD;

    for (int b0 = 0; b0 < NB; b0 += G) {
        conv_k<<<2048, 256, 0, stream>>>(x + (size_t)b0 * SD, XB, (size_t)G * SD);
        transpose_k<<<dim3(SS / 64, DD / 64, G), 256, 0, stream>>>(
            state + (size_t)b0 * SD, ST, SB, SD, sST, sXB);

        // K1: scoresT[t][s] = xbf . statebf^T   (bf16 out into P), 256^2 tile
        gemm256<0><<<dim3(SS / 256, TT / 256, G), 512, 0, stream>>>(
            XB, SB, P, DD, DD, SS, DD, sXB, sXB, sP);

        // K2+K3 fused: window softmax + sparse w[t][d] = p^T statebf (into W)
        softmax1w<<<dim3(TT, G), 256, 0, stream>>>(
            P, x, state, SB, W, src, b0, sP, sXB, sW);

        // transpose: w [t][d] -> wT [d][t] (into P region; scores dead)
        transpose_bf<<<dim3(TT / 64, DD / 64, G), 256, 0, stream>>>(W, P, sW, sP);

        // K4: softmax over t per row e; attnT into W (w dead)
        softmax2_k<<<dim3(DD, G), 256, 0, stream>>>(P, W, src, b0, sP, sW);

        // K5: out[e][d] = attnT . stateT^T   (fp32 out, direct), 128^2 tile
        gemm_nt<1><<<dim3(DD / 128, DD / 128, G), 256, 0, stream>>>(
            W, ST, out + (size_t)b0 * DD * DD, TT, SS, DD, TT, sW, sST, (size_t)DD * DD);
    }
}